// Round 16
// baseline (164.806 us; speedup 1.0000x reference)
//
#include <hip/hip_runtime.h>

#define NROWS 8192
#define BBND  32
#define CBND  512
#define JQ    4096            // j-range per block (2 halves)
#define JSTEP 128             // j per supertile round
#define NR    (JQ / JSTEP)    // 32 rounds
#define ABUFB 16384           // A LDS buffer bytes (64 rows x 256B)

typedef unsigned short u16;
typedef unsigned int   u32;
typedef __bf16 bf16x8 __attribute__((ext_vector_type(8)));
typedef float  f32x4  __attribute__((ext_vector_type(4)));
typedef float  f32x16 __attribute__((ext_vector_type(16)));
typedef u32    u32x4  __attribute__((ext_vector_type(4)));
typedef u32    u32x2  __attribute__((ext_vector_type(2)));

#define ZERO4  (f32x4){0.f,0.f,0.f,0.f}
#define ZERO16 (f32x16){0.f,0.f,0.f,0.f,0.f,0.f,0.f,0.f,0.f,0.f,0.f,0.f,0.f,0.f,0.f,0.f}

// raw barrier: drain LDS ops, keep global loads in flight (no vmcnt drain)
#define BAR asm volatile("s_waitcnt lgkmcnt(0)\n\ts_barrier" ::: "memory")

static __device__ inline u16 f2bf(float f) {
    unsigned u = __builtin_bit_cast(unsigned, f);
    unsigned r = (u + 0x7FFFu + ((u >> 16) & 1u)) >> 16;
    return (u16)r;
}

static __device__ inline float pow14(float base) {
    return __builtin_amdgcn_exp2f(1.4f * __builtin_amdgcn_logf(base));
}

static __device__ inline float adj_eval(float dot, float sij) {
    float x = fabsf(2.f * dot - sij);
    float base = fmaxf(1.f - x * (1.f / 32.f), 0.f);
    return pow14(base);
}

static __device__ inline float sigmoidf_fast(float v) {
    float e = __builtin_amdgcn_exp2f(-1.44269504f * v);
    return 1.f / (1.f + e);
}

static __device__ inline u32 cvtpk(float a, float b) {
    u32 r;
    asm("v_cvt_pk_bf16_f32 %0, %1, %2" : "=v"(r) : "v"(a), "v"(b));
    return r;
}

static __device__ inline f32x4 MFMA16(bf16x8 a, bf16x8 b, f32x4 c) {
    return __builtin_amdgcn_mfma_f32_16x16x32_bf16(a, b, c, 0, 0, 0);
}
static __device__ inline f32x16 MFMA32(bf16x8 a, bf16x8 b, f32x16 c) {
    return __builtin_amdgcn_mfma_f32_32x32x16_bf16(a, b, c, 0, 0, 0);
}

// ---------------- prep: row sums of bbn + bf16 copy ----------------
__global__ __launch_bounds__(256) void k_prep_rows(const float* __restrict__ bbn,
                                                   float* __restrict__ s,
                                                   u16* __restrict__ bbn_bf) {
    int i = blockIdx.x * 256 + threadIdx.x;
    if (i >= NROWS) return;
    const f32x4* row = reinterpret_cast<const f32x4*>(bbn + i * BBND);
    float sum = 0.f;
    u16* dst = bbn_bf + i * BBND;
#pragma unroll
    for (int q = 0; q < 8; ++q) {
        f32x4 v = row[q];
#pragma unroll
        for (int e = 0; e < 4; ++e) {
            sum += v[e];
            dst[q * 4 + e] = f2bf(v[e]);
        }
    }
    s[i] = sum;
}

// ---------------- prep: W transpose -> bf16 ----------------
__global__ __launch_bounds__(256) void k_prep_wt(const float* __restrict__ W,
                                                 u16* __restrict__ WT) {
    int idx = blockIdx.x * 256 + threadIdx.x;   // over 512*512
    int c = idx >> 9, k = idx & 511;
    WT[idx] = f2bf(W[k * CBND + c]);            // WT[c][k]
}

// ---------------- degree: d_i = sum_j adj_ij ; dinv = rsqrt(d+eps) ----------------
__global__ __launch_bounds__(512) void k_deg(const u16* __restrict__ bbn_bf,
                                             const float* __restrict__ s,
                                             float* __restrict__ dinv) {
    __shared__ float part[8][16];
    int ibase = blockIdx.x * 16;
    int tid = threadIdx.x;
    int w = tid >> 6, l = tid & 63, lg = l >> 4, lr = l & 15;

    bf16x8 afrag = *reinterpret_cast<const bf16x8*>(bbn_bf + (ibase + lr) * BBND + lg * 8);
    float si[4];
#pragma unroll
    for (int r = 0; r < 4; ++r) si[r] = s[ibase + lg * 4 + r];

    float dacc[4] = {0.f, 0.f, 0.f, 0.f};
    int j0 = w * (NROWS / 8);
    for (int jt = 0; jt < NROWS / 8; jt += 16) {
        int jb = j0 + jt;
        bf16x8 bfrag = *reinterpret_cast<const bf16x8*>(bbn_bf + (jb + lr) * BBND + lg * 8);
        f32x4 dot = MFMA16(afrag, bfrag, ZERO4);
        float sj = s[jb + lr];
#pragma unroll
        for (int r = 0; r < 4; ++r) dacc[r] += adj_eval(dot[r], si[r] + sj);
    }
#pragma unroll
    for (int off = 1; off < 16; off <<= 1)
#pragma unroll
        for (int r = 0; r < 4; ++r) dacc[r] += __shfl_xor(dacc[r], off, 64);

    if (lr == 0) {
#pragma unroll
        for (int r = 0; r < 4; ++r) part[w][lg * 4 + r] = dacc[r];
    }
    __syncthreads();
    if (tid < 16) {
        float d = 0.f;
#pragma unroll
        for (int q = 0; q < 8; ++q) d += part[q][tid];
        dinv[ibase + tid] = rsqrtf(d + 1e-8f);
    }
}

// ---------------- fc: g_blk[(j>>3)*512 + c][j&7] = dinv_j * (cbn@W + b)[j][c] ----------------
// LDS-staged (round-14, proven): one block per 64-j tile, cbn tile bf16 in LDS
// once, consumed by all 8 c-quadrants -> cbn read from HBM exactly once.
__global__ __launch_bounds__(512) void k_fc(const float* __restrict__ cbn,
                                            const u16* __restrict__ WT,
                                            const float* __restrict__ bvec,
                                            const float* __restrict__ dinv,
                                            u16* __restrict__ g_blk) {
    __shared__ __align__(16) u16 Clds[64 * 512];   // 64 j-rows x 512 k (bf16)
    int jcol = blockIdx.x * 64;
    int tid = threadIdx.x;
    int w = tid >> 6, l = tid & 63, lg = l >> 4, lr = l & 15;
    int wq = w & 3, jh = w >> 2;

    char* Cl = (char*)&Clds[0];

#pragma unroll
    for (int p = 0; p < 8; ++p) {
        int gidx = p * 512 + tid;
        int row = gidx >> 6, sl = gidx & 63;
        const f32x4* src = reinterpret_cast<const f32x4*>(cbn + (jcol + row) * CBND + sl * 8);
        f32x4 v0 = src[0], v1 = src[1];
        bf16x8 bv;
#pragma unroll
        for (int e = 0; e < 4; ++e) { bv[e] = (__bf16)v0[e]; bv[e + 4] = (__bf16)v1[e]; }
        *reinterpret_cast<bf16x8*>(Cl + row * 1024 + ((sl ^ (row & 7)) << 4)) = bv;
    }
    __syncthreads();

    int r7 = lr & 7;
    for (int cb = 0; cb < 8; ++cb) {
        int crow = cb * 64 + wq * 16;
        f32x4 acc0 = ZERO4, acc1 = ZERO4;
        for (int k0 = 0; k0 < CBND; k0 += 32) {
            bf16x8 afrag = *reinterpret_cast<const bf16x8*>(WT + (crow + lr) * CBND + k0 + lg * 8);
            int slot = (k0 >> 3) + lg;
            int row0 = jh * 32 + lr;
            bf16x8 b0 = *reinterpret_cast<const bf16x8*>(Cl + row0 * 1024 + ((slot ^ r7) << 4));
            bf16x8 b1 = *reinterpret_cast<const bf16x8*>(Cl + (row0 + 16) * 1024 + ((slot ^ r7) << 4));
            acc0 = MFMA16(afrag, b0, acc0);
            acc1 = MFMA16(afrag, b1, acc1);
        }
#pragma unroll
        for (int f = 0; f < 2; ++f) {
            f32x4 af = f ? acc1 : acc0;
#pragma unroll
            for (int r = 0; r < 4; ++r) {
                int c = crow + lg * 4 + r;
                int j = jcol + jh * 32 + f * 16 + lr;
                float val = af[r] + bvec[c];
                g_blk[(((j >> 3) * 512 + c) << 3) + (j & 7)] = f2bf(val * dinv[j]);
            }
        }
    }
}

// ---------------- conv: partial sums P[jh] = sum_{j in half} adj_ij * g[:,j] ----------------
// Round-15 structure with JSTEP doubled 64 -> 128: barriers halved (64 -> 32),
// per-st glue amortized over 2x work. Block 1024 thr (16 waves), tile 64i x
// 512c, wave acc 64i x 32c (no B duplication). Per st: gen 2 units/wave
// (r10's proven 2-unit pattern), A-tile 64 x 256B dbuf (32KB LDS), CONVP =
// 8 k-steps x 2 i-frags = 16 MFMA32, B single-buffered (8 x u32x4 = 32 VGPR;
// LOADB -> GEN2 -> CONVP covers L2 latency). Regs ~104 < 128 @ (1024,4).
// Per-element j-order (st asc, t asc, octet-pair chunks) identical to r15 ->
// sums bit-identical (absmax 0.00390625).

#define LOADB(T, R) { \
    const char* p = gB + (long)(T) * 131072; \
    R##0 = *reinterpret_cast<const u32x4*>(p); \
    R##1 = *reinterpret_cast<const u32x4*>(p + 16384); \
    R##2 = *reinterpret_cast<const u32x4*>(p + 32768); \
    R##3 = *reinterpret_cast<const u32x4*>(p + 49152); \
    R##4 = *reinterpret_cast<const u32x4*>(p + 65536); \
    R##5 = *reinterpret_cast<const u32x4*>(p + 81920); \
    R##6 = *reinterpret_cast<const u32x4*>(p + 98304); \
    R##7 = *reinterpret_cast<const u32x4*>(p + 114688); \
}

#define GEN2(ST, WB) { \
    int jg0 = jbase + (ST) * JSTEP + jq8 * 32; \
    bf16x8 fJ0 = *reinterpret_cast<const bf16x8*>(bbn_bf + (jg0 + lr) * BBND + lg * 8); \
    f32x4 sj0 = *reinterpret_cast<const f32x4*>(s + jg0 + lg * 4); \
    bf16x8 fJ1 = *reinterpret_cast<const bf16x8*>(bbn_bf + (jg0 + 16 + lr) * BBND + lg * 8); \
    f32x4 sj1 = *reinterpret_cast<const f32x4*>(s + jg0 + 16 + lg * 4); \
    f32x4 d0 = MFMA16(fJ0, fragI, ZERO4); \
    f32x4 d1 = MFMA16(fJ1, fragI, ZERO4); \
    u32 p00 = cvtpk(adj_eval(d0[0], si + sj0[0]), adj_eval(d0[1], si + sj0[1])); \
    u32 p01 = cvtpk(adj_eval(d0[2], si + sj0[2]), adj_eval(d0[3], si + sj0[3])); \
    u32 p10 = cvtpk(adj_eval(d1[0], si + sj1[0]), adj_eval(d1[1], si + sj1[1])); \
    u32 p11 = cvtpk(adj_eval(d1[2], si + sj1[2]), adj_eval(d1[3], si + sj1[3])); \
    char* Aw = Ab + (WB) * ABUFB; \
    *reinterpret_cast<u32x2*>(Aw + gw0) = (u32x2){p00, p01}; \
    *reinterpret_cast<u32x2*>(Aw + gw1) = (u32x2){p10, p11}; \
}

#define CSTEP(Ar, AOFF, R) { \
    bf16x8 tl = *reinterpret_cast<const bf16x8*>((Ar) + (AOFF)); \
    bf16x8 th = *reinterpret_cast<const bf16x8*>((Ar) + (AOFF) + 8192); \
    c00 = MFMA32(tl, __builtin_bit_cast(bf16x8, R), c00); \
    c10 = MFMA32(th, __builtin_bit_cast(bf16x8, R), c10); \
}

#define CONVP(RB, R) { \
    const char* Ar = Ab + (RB) * ABUFB; \
    CSTEP(Ar, a0, R##0); \
    CSTEP(Ar, a1, R##1); \
    CSTEP(Ar, a2, R##2); \
    CSTEP(Ar, a3, R##3); \
    CSTEP(Ar, a4, R##4); \
    CSTEP(Ar, a5, R##5); \
    CSTEP(Ar, a6, R##6); \
    CSTEP(Ar, a7, R##7); \
}

#define EPI(ACC, IH) { \
    _Pragma("unroll") \
    for (int reg = 0; reg < 16; ++reg) { \
        int rowD = (reg & 3) + 8 * (reg >> 2) + 4 * lh; \
        Pq[(long)(ibase + (IH) * 32 + rowD) * CBND + w * 32 + l31] = ACC[reg]; \
    } \
}

__global__ __launch_bounds__(1024, 4) void k_conv(const u16* __restrict__ bbn_bf,
                                                  const float* __restrict__ s,
                                                  const u16* __restrict__ g_blk,
                                                  float* __restrict__ P) {
    __shared__ __align__(16) u16 Alds[2][64 * 128];  // 2 x 16KB supertiles

    int bx = blockIdx.x;
    int jq = bx & 1;                   // j-half; constant per XCD (stride-8 dispatch)
    int it = bx >> 1;                  // 0..127
    int ibase = it * 64;
    int jbase = jq * JQ;

    int tid = threadIdx.x;
    int w = tid >> 6, l = tid & 63;
    int lr = l & 15, lg = l >> 4, l31 = l & 31, lh = l >> 5;
    int iq = w & 3, jq8 = w >> 2;      // gen: 4 i-quads x 4 j-quarters (2 units each)

    // gen hoists
    bf16x8 fragI = *reinterpret_cast<const bf16x8*>(bbn_bf + (ibase + iq * 16 + lr) * BBND + lg * 8);
    float si = s[ibase + iq * 16 + lr];

    char* Ab = (char*)&Alds[0][0];
    float* Pq = P + (long)jq * (NROWS * CBND);

    // B global base: octet (jbase/8 + ST*16 + t*2 + lh), c = w*32 + l31
    const char* gB = (const char*)g_blk + (long)jbase * 1024 + lh * 8192
                   + (w * 32 + l31) * 16;

    // A-frag reads: rows l31 (i-lo) / l31+32 (i-hi, +8192B), 256B rows,
    // k-step t slot = 2t+lh, phys = slot ^ (row&7) (XOR hits low 3 bits only;
    // (l31+32)&7 == l31&7 so i-hi shares the XOR).
    int r7 = l31 & 7;
    int abase = l31 * 256;
    int a0 = abase + (((0  + lh) ^ r7) << 4);
    int a1 = abase + (((2  + lh) ^ r7) << 4);
    int a2 = abase + (((4  + lh) ^ r7) << 4);
    int a3 = abase + (((6  + lh) ^ r7) << 4);
    int a4 = abase + (((8  + lh) ^ r7) << 4);
    int a5 = abase + (((10 + lh) ^ r7) << 4);
    int a6 = abase + (((12 + lh) ^ r7) << 4);
    int a7 = abase + (((14 + lh) ^ r7) << 4);

    // gen writes: row = iq*16+lr; unit u slot = jq8*4 + u*2 + (lg>>1),
    // phys = slot ^ (row&7), byte +(lg&1)*8
    int grow = iq * 16 + lr;
    int r7g = grow & 7;
    int gw0 = grow * 256 + (((jq8 * 4 + 0 + (lg >> 1)) ^ r7g) << 4) + (lg & 1) * 8;
    int gw1 = grow * 256 + (((jq8 * 4 + 2 + (lg >> 1)) ^ r7g) << 4) + (lg & 1) * 8;

    f32x16 c00 = ZERO16, c10 = ZERO16;

    u32x4 rB0, rB1, rB2, rB3, rB4, rB5, rB6, rB7;

    // prologue: supertile 0 into buf0
    GEN2(0, 0);
    BAR;

    for (int st = 0; st < NR; ++st) {
        int rb = st & 1, wb = rb ^ 1;
        LOADB(st, rB);                       // B(st): latency covered by GEN2
        if (st + 1 < NR) GEN2(st + 1, wb);
        CONVP(rb, rB);
        BAR;
    }

    EPI(c00, 0);
    EPI(c10, 1);
}

// ---------------- combine: out = sigmoid(dinv_i * (P0 + P1)) ----------------
__global__ __launch_bounds__(256) void k_comb(const float* __restrict__ dinv,
                                              const float* __restrict__ P,
                                              float* __restrict__ out) {
    int idx = blockIdx.x * 256 + threadIdx.x;   // f32x4 index; 1,048,576 total
    float di = dinv[idx >> 7];
    f32x4 a = *reinterpret_cast<const f32x4*>(P + (long)idx * 4);
    f32x4 b = *reinterpret_cast<const f32x4*>(P + (long)NROWS * CBND + (long)idx * 4);
    f32x4 v;
#pragma unroll
    for (int e = 0; e < 4; ++e) v[e] = sigmoidf_fast((a[e] + b[e]) * di);
    *reinterpret_cast<f32x4*>(out + (long)idx * 4) = v;
}

extern "C" void kernel_launch(void* const* d_in, const int* in_sizes, int n_in,
                              void* d_out, int out_size, void* d_ws, size_t ws_size,
                              hipStream_t stream) {
    const float* bbn = (const float*)d_in[0];   // [8192,32]
    const float* cbn = (const float*)d_in[1];   // [8192,512]
    const float* W   = (const float*)d_in[2];   // [512,512]
    const float* b   = (const float*)d_in[3];   // [512]
    float* out = (float*)d_out;                 // [8192,512] f32

    char* ws = (char*)d_ws;
    float* s      = (float*)ws;  ws += NROWS * 4;
    float* dinv   = (float*)ws;  ws += NROWS * 4;
    u16* bbn_bf   = (u16*)ws;    ws += NROWS * BBND * 2;
    u16* WT       = (u16*)ws;    ws += CBND * CBND * 2;
    u16* g_blk    = (u16*)ws;    ws += (size_t)CBND * NROWS * 2;
    float* P      = (float*)ws;  ws += (size_t)2 * NROWS * CBND * 4;   // 32MB partials

    k_prep_rows<<<NROWS / 256, 256, 0, stream>>>(bbn, s, bbn_bf);
    k_prep_wt<<<(CBND * CBND) / 256, 256, 0, stream>>>(W, WT);
    k_deg<<<NROWS / 16, 512, 0, stream>>>(bbn_bf, s, dinv);
    k_fc<<<NROWS / 64, 512, 0, stream>>>(cbn, WT, b, dinv, g_blk);
    k_conv<<<(NROWS / 64) * 2, 1024, 0, stream>>>(bbn_bf, s, g_blk, P);
    k_comb<<<(NROWS * CBND / 4) / 256, 256, 0, stream>>>(dinv, P, out);
}

// Round 17
// 151.908 us; speedup vs baseline: 1.0849x; 1.0849x over previous
//
#include <hip/hip_runtime.h>

#define NROWS 8192
#define BBND  32
#define CBND  512
#define JQ    4096            // j-range per block (2 halves)
#define NR    64              // rounds of 64j per block
#define ABUFB 8192            // A LDS buffer bytes (64 rows x 128B)

typedef unsigned short u16;
typedef unsigned int   u32;
typedef __bf16 bf16x8 __attribute__((ext_vector_type(8)));
typedef float  f32x4  __attribute__((ext_vector_type(4)));
typedef float  f32x16 __attribute__((ext_vector_type(16)));
typedef u32    u32x4  __attribute__((ext_vector_type(4)));
typedef u32    u32x2  __attribute__((ext_vector_type(2)));

#define ZERO4  (f32x4){0.f,0.f,0.f,0.f}
#define ZERO16 (f32x16){0.f,0.f,0.f,0.f,0.f,0.f,0.f,0.f,0.f,0.f,0.f,0.f,0.f,0.f,0.f,0.f}

// raw barrier: drain LDS ops, keep global loads in flight (no vmcnt drain)
#define BAR asm volatile("s_waitcnt lgkmcnt(0)\n\ts_barrier" ::: "memory")

static __device__ inline u16 f2bf(float f) {
    unsigned u = __builtin_bit_cast(unsigned, f);
    unsigned r = (u + 0x7FFFu + ((u >> 16) & 1u)) >> 16;
    return (u16)r;
}

static __device__ inline float pow14(float base) {
    return __builtin_amdgcn_exp2f(1.4f * __builtin_amdgcn_logf(base));
}

static __device__ inline float adj_eval(float dot, float sij) {
    float x = fabsf(2.f * dot - sij);
    float base = fmaxf(1.f - x * (1.f / 32.f), 0.f);
    return pow14(base);
}

static __device__ inline float sigmoidf_fast(float v) {
    float e = __builtin_amdgcn_exp2f(-1.44269504f * v);
    return 1.f / (1.f + e);
}

static __device__ inline u32 cvtpk(float a, float b) {
    u32 r;
    asm("v_cvt_pk_bf16_f32 %0, %1, %2" : "=v"(r) : "v"(a), "v"(b));
    return r;
}

static __device__ inline f32x4 MFMA16(bf16x8 a, bf16x8 b, f32x4 c) {
    return __builtin_amdgcn_mfma_f32_16x16x32_bf16(a, b, c, 0, 0, 0);
}
static __device__ inline f32x16 MFMA32(bf16x8 a, bf16x8 b, f32x16 c) {
    return __builtin_amdgcn_mfma_f32_32x32x16_bf16(a, b, c, 0, 0, 0);
}

// ---------------- prep: row sums of bbn + bf16 copy ----------------
__global__ __launch_bounds__(256) void k_prep_rows(const float* __restrict__ bbn,
                                                   float* __restrict__ s,
                                                   u16* __restrict__ bbn_bf) {
    int i = blockIdx.x * 256 + threadIdx.x;
    if (i >= NROWS) return;
    const f32x4* row = reinterpret_cast<const f32x4*>(bbn + i * BBND);
    float sum = 0.f;
    u16* dst = bbn_bf + i * BBND;
#pragma unroll
    for (int q = 0; q < 8; ++q) {
        f32x4 v = row[q];
#pragma unroll
        for (int e = 0; e < 4; ++e) {
            sum += v[e];
            dst[q * 4 + e] = f2bf(v[e]);
        }
    }
    s[i] = sum;
}

// ---------------- prep: W transpose -> bf16 ----------------
__global__ __launch_bounds__(256) void k_prep_wt(const float* __restrict__ W,
                                                 u16* __restrict__ WT) {
    int idx = blockIdx.x * 256 + threadIdx.x;   // over 512*512
    int c = idx >> 9, k = idx & 511;
    WT[idx] = f2bf(W[k * CBND + c]);            // WT[c][k]
}

// ---------------- degree: d_i = sum_j adj_ij ; dinv = rsqrt(d+eps) ----------------
// 1024-thr blocks (16 waves), grid 512 -> 2 blocks/CU = 32 waves/CU (2x TLP vs
// r15's 512-thr version). Each wave sweeps 512 j (32 iters). Same per-(i,j)
// math; partial-sum regrouping perturbs dinv only at ulp level.
__global__ __launch_bounds__(1024) void k_deg(const u16* __restrict__ bbn_bf,
                                              const float* __restrict__ s,
                                              float* __restrict__ dinv) {
    __shared__ float part[16][16];
    int ibase = blockIdx.x * 16;
    int tid = threadIdx.x;
    int w = tid >> 6, l = tid & 63, lg = l >> 4, lr = l & 15;

    bf16x8 afrag = *reinterpret_cast<const bf16x8*>(bbn_bf + (ibase + lr) * BBND + lg * 8);
    float si[4];
#pragma unroll
    for (int r = 0; r < 4; ++r) si[r] = s[ibase + lg * 4 + r];

    float dacc[4] = {0.f, 0.f, 0.f, 0.f};
    int j0 = w * (NROWS / 16);
    for (int jt = 0; jt < NROWS / 16; jt += 16) {
        int jb = j0 + jt;
        bf16x8 bfrag = *reinterpret_cast<const bf16x8*>(bbn_bf + (jb + lr) * BBND + lg * 8);
        f32x4 dot = MFMA16(afrag, bfrag, ZERO4);
        float sj = s[jb + lr];
#pragma unroll
        for (int r = 0; r < 4; ++r) dacc[r] += adj_eval(dot[r], si[r] + sj);
    }
#pragma unroll
    for (int off = 1; off < 16; off <<= 1)
#pragma unroll
        for (int r = 0; r < 4; ++r) dacc[r] += __shfl_xor(dacc[r], off, 64);

    if (lr == 0) {
#pragma unroll
        for (int r = 0; r < 4; ++r) part[w][lg * 4 + r] = dacc[r];
    }
    __syncthreads();
    if (tid < 16) {
        float d = 0.f;
#pragma unroll
        for (int q = 0; q < 16; ++q) d += part[q][tid];
        dinv[ibase + tid] = rsqrtf(d + 1e-8f);
    }
}

// ---------------- fc: g_blk[(j>>3)*512 + c][j&7] = dinv_j * (cbn@W + b)[j][c] ----------------
// LDS-staged (round-14, proven) + c-half split: grid 256 = 128 j-tiles x 2
// c-halves -> full chip (was 128 blocks on 256 CUs). Each block stages its
// 64x512 cbn tile in LDS once and does 4 c-quadrants. cbn is L3-resident so
// the duplicate stage costs L3 reads, not HBM. g values bit-identical.
__global__ __launch_bounds__(512) void k_fc(const float* __restrict__ cbn,
                                            const u16* __restrict__ WT,
                                            const float* __restrict__ bvec,
                                            const float* __restrict__ dinv,
                                            u16* __restrict__ g_blk) {
    __shared__ __align__(16) u16 Clds[64 * 512];   // 64 j-rows x 512 k (bf16)
    int bx = blockIdx.x;
    int ch = bx & 1;
    int jcol = (bx >> 1) * 64;
    int tid = threadIdx.x;
    int w = tid >> 6, l = tid & 63, lg = l >> 4, lr = l & 15;
    int wq = w & 3, jh = w >> 2;

    char* Cl = (char*)&Clds[0];

#pragma unroll
    for (int p = 0; p < 8; ++p) {
        int gidx = p * 512 + tid;
        int row = gidx >> 6, sl = gidx & 63;
        const f32x4* src = reinterpret_cast<const f32x4*>(cbn + (jcol + row) * CBND + sl * 8);
        f32x4 v0 = src[0], v1 = src[1];
        bf16x8 bv;
#pragma unroll
        for (int e = 0; e < 4; ++e) { bv[e] = (__bf16)v0[e]; bv[e + 4] = (__bf16)v1[e]; }
        *reinterpret_cast<bf16x8*>(Cl + row * 1024 + ((sl ^ (row & 7)) << 4)) = bv;
    }
    __syncthreads();

    int r7 = lr & 7;
    for (int q = 0; q < 4; ++q) {
        int cb = ch * 4 + q;
        int crow = cb * 64 + wq * 16;
        f32x4 acc0 = ZERO4, acc1 = ZERO4;
        for (int k0 = 0; k0 < CBND; k0 += 32) {
            bf16x8 afrag = *reinterpret_cast<const bf16x8*>(WT + (crow + lr) * CBND + k0 + lg * 8);
            int slot = (k0 >> 3) + lg;
            int row0 = jh * 32 + lr;
            bf16x8 b0 = *reinterpret_cast<const bf16x8*>(Cl + row0 * 1024 + ((slot ^ r7) << 4));
            bf16x8 b1 = *reinterpret_cast<const bf16x8*>(Cl + (row0 + 16) * 1024 + ((slot ^ r7) << 4));
            acc0 = MFMA16(afrag, b0, acc0);
            acc1 = MFMA16(afrag, b1, acc1);
        }
#pragma unroll
        for (int f = 0; f < 2; ++f) {
            f32x4 af = f ? acc1 : acc0;
#pragma unroll
            for (int r = 0; r < 4; ++r) {
                int c = crow + lg * 4 + r;
                int j = jcol + jh * 32 + f * 16 + lr;
                float val = af[r] + bvec[c];
                g_blk[(((j >> 3) * 512 + c) << 3) + (j & 7)] = f2bf(val * dinv[j]);
            }
        }
    }
}

// ---------------- conv: partial sums P[jh] = sum_{j in half} adj_ij * g[:,j] ----------------
// ROUND-15 VERBATIM (best measured: 93.1us, absmax 0.00390625).
// Block 1024 thr (16 waves), tile 64i x 512c, wave acc 64i x 32c (no B dup).
// JSTEP 64, dbuf A LDS, lgkmcnt-only barrier, B reg-prefetched from g_blk.

#define LOADB(T, R) { \
    const char* p = gB + (long)(T) * 65536; \
    R##0 = *reinterpret_cast<const u32x4*>(p); \
    R##1 = *reinterpret_cast<const u32x4*>(p + 16384); \
    R##2 = *reinterpret_cast<const u32x4*>(p + 32768); \
    R##3 = *reinterpret_cast<const u32x4*>(p + 49152); \
}

#define GEN(ST, WB) { \
    int jg = jbase + (ST) * 64 + jq8 * 16; \
    bf16x8 fJ = *reinterpret_cast<const bf16x8*>(bbn_bf + (jg + lr) * BBND + lg * 8); \
    f32x4 sj = *reinterpret_cast<const f32x4*>(s + jg + lg * 4); \
    f32x4 dot = MFMA16(fJ, fragI, ZERO4); \
    u32 p0 = cvtpk(adj_eval(dot[0], si + sj[0]), adj_eval(dot[1], si + sj[1])); \
    u32 p1 = cvtpk(adj_eval(dot[2], si + sj[2]), adj_eval(dot[3], si + sj[3])); \
    *reinterpret_cast<u32x2*>(Ab + (WB) * ABUFB + gw) = (u32x2){p0, p1}; \
}

#define CONVP(RB, R) { \
    const char* Ar = Ab + (RB) * ABUFB; \
    bf16x8 t0l = *reinterpret_cast<const bf16x8*>(Ar + a0); \
    bf16x8 t0h = *reinterpret_cast<const bf16x8*>(Ar + a0 + 4096); \
    c00 = MFMA32(t0l, __builtin_bit_cast(bf16x8, R##0), c00); \
    c10 = MFMA32(t0h, __builtin_bit_cast(bf16x8, R##0), c10); \
    bf16x8 t1l = *reinterpret_cast<const bf16x8*>(Ar + a1); \
    bf16x8 t1h = *reinterpret_cast<const bf16x8*>(Ar + a1 + 4096); \
    c00 = MFMA32(t1l, __builtin_bit_cast(bf16x8, R##1), c00); \
    c10 = MFMA32(t1h, __builtin_bit_cast(bf16x8, R##1), c10); \
    bf16x8 t2l = *reinterpret_cast<const bf16x8*>(Ar + a2); \
    bf16x8 t2h = *reinterpret_cast<const bf16x8*>(Ar + a2 + 4096); \
    c00 = MFMA32(t2l, __builtin_bit_cast(bf16x8, R##2), c00); \
    c10 = MFMA32(t2h, __builtin_bit_cast(bf16x8, R##2), c10); \
    bf16x8 t3l = *reinterpret_cast<const bf16x8*>(Ar + a3); \
    bf16x8 t3h = *reinterpret_cast<const bf16x8*>(Ar + a3 + 4096); \
    c00 = MFMA32(t3l, __builtin_bit_cast(bf16x8, R##3), c00); \
    c10 = MFMA32(t3h, __builtin_bit_cast(bf16x8, R##3), c10); \
}

#define EPI(ACC, IH) { \
    _Pragma("unroll") \
    for (int reg = 0; reg < 16; ++reg) { \
        int rowD = (reg & 3) + 8 * (reg >> 2) + 4 * lh; \
        Pq[(long)(ibase + (IH) * 32 + rowD) * CBND + w * 32 + l31] = ACC[reg]; \
    } \
}

__global__ __launch_bounds__(1024, 4) void k_conv(const u16* __restrict__ bbn_bf,
                                                  const float* __restrict__ s,
                                                  const u16* __restrict__ g_blk,
                                                  float* __restrict__ P) {
    __shared__ __align__(16) u16 Alds[2][64 * 64];   // 2 x 8KB supertiles

    int bx = blockIdx.x;
    int jq = bx & 1;                   // j-half; constant per XCD (stride-8 dispatch)
    int it = bx >> 1;                  // 0..127
    int ibase = it * 64;
    int jbase = jq * JQ;

    int tid = threadIdx.x;
    int w = tid >> 6, l = tid & 63;
    int lr = l & 15, lg = l >> 4, l31 = l & 31, lh = l >> 5;
    int iq = w & 3, jq8 = w >> 2;      // gen wave tile: 16i x 16j (4x4 waves)

    // gen hoists
    bf16x8 fragI = *reinterpret_cast<const bf16x8*>(bbn_bf + (ibase + iq * 16 + lr) * BBND + lg * 8);
    float si = s[ibase + iq * 16 + lr];

    char* Ab = (char*)&Alds[0][0];
    float* Pq = P + (long)jq * (NROWS * CBND);

    // B global base: octet (jbase/8 + T*8 + t*2 + lh), c = w*32 + l31
    const char* gB = (const char*)g_blk + (long)jbase * 1024 + lh * 8192
                   + (w * 32 + l31) * 16;

    // A-frag reads: rows l31 (i-lo) / l31+32 (i-hi, +4096B), k-step t slot = 2t+lh,
    // phys = slot ^ (row&7); (l31+32)&7 == l31&7 so i-hi shares the XOR.
    int r7 = l31 & 7;
    int abase = l31 * 128;
    int a0 = abase + (((0 + lh) ^ r7) << 4);
    int a1 = abase + (((2 + lh) ^ r7) << 4);
    int a2 = abase + (((4 + lh) ^ r7) << 4);
    int a3 = abase + (((6 + lh) ^ r7) << 4);

    // gen write: row = iq*16+lr, logical slot = jq8*2 + (lg>>1), byte +(lg&1)*8
    int grow = iq * 16 + lr;
    int gw = grow * 128 + (((jq8 * 2 + (lg >> 1)) ^ (grow & 7)) << 4) + (lg & 1) * 8;

    f32x16 c00 = ZERO16, c10 = ZERO16;

    u32x4 rA0, rA1, rA2, rA3;
    u32x4 rB0, rB1, rB2, rB3;

    // prologue: supertile 0 into buf0, B(st=0) into rA
    GEN(0, 0);
    LOADB(0, rA);
    BAR;

    for (int st2 = 0; st2 < NR; st2 += 2) {
        LOADB(st2 + 1, rB);
        GEN(st2 + 1, 1);
        CONVP(0, rA);
        BAR;
        int tn = (st2 + 2 < NR) ? st2 + 2 : NR - 1;   // tail: redundant, never read
        LOADB(tn, rA);
        GEN(tn, 0);
        CONVP(1, rB);
        BAR;
    }

    EPI(c00, 0);
    EPI(c10, 1);
}

// ---------------- combine: out = sigmoid(dinv_i * (P0 + P1)) ----------------
__global__ __launch_bounds__(256) void k_comb(const float* __restrict__ dinv,
                                              const float* __restrict__ P,
                                              float* __restrict__ out) {
    int idx = blockIdx.x * 256 + threadIdx.x;   // f32x4 index; 1,048,576 total
    float di = dinv[idx >> 7];
    f32x4 a = *reinterpret_cast<const f32x4*>(P + (long)idx * 4);
    f32x4 b = *reinterpret_cast<const f32x4*>(P + (long)NROWS * CBND + (long)idx * 4);
    f32x4 v;
#pragma unroll
    for (int e = 0; e < 4; ++e) v[e] = sigmoidf_fast((a[e] + b[e]) * di);
    *reinterpret_cast<f32x4*>(out + (long)idx * 4) = v;
}

extern "C" void kernel_launch(void* const* d_in, const int* in_sizes, int n_in,
                              void* d_out, int out_size, void* d_ws, size_t ws_size,
                              hipStream_t stream) {
    const float* bbn = (const float*)d_in[0];   // [8192,32]
    const float* cbn = (const float*)d_in[1];   // [8192,512]
    const float* W   = (const float*)d_in[2];   // [512,512]
    const float* b   = (const float*)d_in[3];   // [512]
    float* out = (float*)d_out;                 // [8192,512] f32

    char* ws = (char*)d_ws;
    float* s      = (float*)ws;  ws += NROWS * 4;
    float* dinv   = (float*)ws;  ws += NROWS * 4;
    u16* bbn_bf   = (u16*)ws;    ws += NROWS * BBND * 2;
    u16* WT       = (u16*)ws;    ws += CBND * CBND * 2;
    u16* g_blk    = (u16*)ws;    ws += (size_t)CBND * NROWS * 2;
    float* P      = (float*)ws;  ws += (size_t)2 * NROWS * CBND * 4;   // 32MB partials

    k_prep_rows<<<NROWS / 256, 256, 0, stream>>>(bbn, s, bbn_bf);
    k_prep_wt<<<(CBND * CBND) / 256, 256, 0, stream>>>(W, WT);
    k_deg<<<NROWS / 16, 1024, 0, stream>>>(bbn_bf, s, dinv);
    k_fc<<<(NROWS / 64) * 2, 512, 0, stream>>>(cbn, WT, b, dinv, g_blk);
    k_conv<<<(NROWS / 64) * 2, 1024, 0, stream>>>(bbn_bf, s, g_blk, P);
    k_comb<<<(NROWS * CBND / 4) / 256, 256, 0, stream>>>(dinv, P, out);
}

// Round 18
// 148.687 us; speedup vs baseline: 1.1084x; 1.0217x over previous
//
#include <hip/hip_runtime.h>

#define NROWS 8192
#define BBND  32
#define CBND  512
#define JQ    4096            // j-range per block (2 halves)
#define NR    64              // rounds of 64j per block
#define ABUFB 8192            // A LDS buffer bytes (64 rows x 128B)

typedef unsigned short u16;
typedef unsigned int   u32;
typedef __bf16 bf16x8 __attribute__((ext_vector_type(8)));
typedef float  f32x4  __attribute__((ext_vector_type(4)));
typedef float  f32x16 __attribute__((ext_vector_type(16)));
typedef u32    u32x4  __attribute__((ext_vector_type(4)));
typedef u32    u32x2  __attribute__((ext_vector_type(2)));

#define ZERO4  (f32x4){0.f,0.f,0.f,0.f}
#define ZERO16 (f32x16){0.f,0.f,0.f,0.f,0.f,0.f,0.f,0.f,0.f,0.f,0.f,0.f,0.f,0.f,0.f,0.f}

// raw barrier: drain LDS ops, keep global loads in flight (no vmcnt drain)
#define BAR asm volatile("s_waitcnt lgkmcnt(0)\n\ts_barrier" ::: "memory")

static __device__ inline u16 f2bf(float f) {
    unsigned u = __builtin_bit_cast(unsigned, f);
    unsigned r = (u + 0x7FFFu + ((u >> 16) & 1u)) >> 16;
    return (u16)r;
}

static __device__ inline float pow14(float base) {
    return __builtin_amdgcn_exp2f(1.4f * __builtin_amdgcn_logf(base));
}

static __device__ inline float adj_eval(float dot, float sij) {
    float x = fabsf(2.f * dot - sij);
    float base = fmaxf(1.f - x * (1.f / 32.f), 0.f);
    return pow14(base);
}

static __device__ inline float sigmoidf_fast(float v) {
    float e = __builtin_amdgcn_exp2f(-1.44269504f * v);
    return 1.f / (1.f + e);
}

static __device__ inline u32 cvtpk(float a, float b) {
    u32 r;
    asm("v_cvt_pk_bf16_f32 %0, %1, %2" : "=v"(r) : "v"(a), "v"(b));
    return r;
}

static __device__ inline f32x4 MFMA16(bf16x8 a, bf16x8 b, f32x4 c) {
    return __builtin_amdgcn_mfma_f32_16x16x32_bf16(a, b, c, 0, 0, 0);
}
static __device__ inline f32x16 MFMA32(bf16x8 a, bf16x8 b, f32x16 c) {
    return __builtin_amdgcn_mfma_f32_32x32x16_bf16(a, b, c, 0, 0, 0);
}

// ---------------- prep: row sums of bbn + bf16 copy ----------------
__global__ __launch_bounds__(256) void k_prep_rows(const float* __restrict__ bbn,
                                                   float* __restrict__ s,
                                                   u16* __restrict__ bbn_bf) {
    int i = blockIdx.x * 256 + threadIdx.x;
    if (i >= NROWS) return;
    const f32x4* row = reinterpret_cast<const f32x4*>(bbn + i * BBND);
    float sum = 0.f;
    u16* dst = bbn_bf + i * BBND;
#pragma unroll
    for (int q = 0; q < 8; ++q) {
        f32x4 v = row[q];
#pragma unroll
        for (int e = 0; e < 4; ++e) {
            sum += v[e];
            dst[q * 4 + e] = f2bf(v[e]);
        }
    }
    s[i] = sum;
}

// ---------------- prep: W transpose -> bf16 ----------------
__global__ __launch_bounds__(256) void k_prep_wt(const float* __restrict__ W,
                                                 u16* __restrict__ WT) {
    int idx = blockIdx.x * 256 + threadIdx.x;   // over 512*512
    int c = idx >> 9, k = idx & 511;
    WT[idx] = f2bf(W[k * CBND + c]);            // WT[c][k]
}

// ---------------- degree: d_i = sum_j adj_ij ; dinv = rsqrt(d+eps) ----------------
// r17 structure (1024 thr, 32 waves/CU) + software-pipelined loads: bfrag/sj
// for iter t+1 issued during iter t -> L2 latency off the serial chain.
// Same values, same summation order -> dinv bit-identical.
__global__ __launch_bounds__(1024) void k_deg(const u16* __restrict__ bbn_bf,
                                              const float* __restrict__ s,
                                              float* __restrict__ dinv) {
    __shared__ float part[16][16];
    int ibase = blockIdx.x * 16;
    int tid = threadIdx.x;
    int w = tid >> 6, l = tid & 63, lg = l >> 4, lr = l & 15;

    bf16x8 afrag = *reinterpret_cast<const bf16x8*>(bbn_bf + (ibase + lr) * BBND + lg * 8);
    float si[4];
#pragma unroll
    for (int r = 0; r < 4; ++r) si[r] = s[ibase + lg * 4 + r];

    float dacc[4] = {0.f, 0.f, 0.f, 0.f};
    int j0 = w * (NROWS / 16);
    bf16x8 nbf = *reinterpret_cast<const bf16x8*>(bbn_bf + (j0 + lr) * BBND + lg * 8);
    float nsj = s[j0 + lr];
    for (int jt = 0; jt < NROWS / 16; jt += 16) {
        bf16x8 bfrag = nbf;
        float sj = nsj;
        if (jt + 16 < NROWS / 16) {
            int jn = j0 + jt + 16;
            nbf = *reinterpret_cast<const bf16x8*>(bbn_bf + (jn + lr) * BBND + lg * 8);
            nsj = s[jn + lr];
        }
        f32x4 dot = MFMA16(afrag, bfrag, ZERO4);
#pragma unroll
        for (int r = 0; r < 4; ++r) dacc[r] += adj_eval(dot[r], si[r] + sj);
    }
#pragma unroll
    for (int off = 1; off < 16; off <<= 1)
#pragma unroll
        for (int r = 0; r < 4; ++r) dacc[r] += __shfl_xor(dacc[r], off, 64);

    if (lr == 0) {
#pragma unroll
        for (int r = 0; r < 4; ++r) part[w][lg * 4 + r] = dacc[r];
    }
    __syncthreads();
    if (tid < 16) {
        float d = 0.f;
#pragma unroll
        for (int q = 0; q < 16; ++q) d += part[q][tid];
        dinv[ibase + tid] = rsqrtf(d + 1e-8f);
    }
}

// ---------------- fc: g_blk[(j>>3)*512 + c][j&7] = dinv_j * (cbn@W + b)[j][c] ----------------
// r17 verbatim: LDS-staged cbn tile + c-half split (grid 256, full chip).
__global__ __launch_bounds__(512) void k_fc(const float* __restrict__ cbn,
                                            const u16* __restrict__ WT,
                                            const float* __restrict__ bvec,
                                            const float* __restrict__ dinv,
                                            u16* __restrict__ g_blk) {
    __shared__ __align__(16) u16 Clds[64 * 512];   // 64 j-rows x 512 k (bf16)
    int bx = blockIdx.x;
    int ch = bx & 1;
    int jcol = (bx >> 1) * 64;
    int tid = threadIdx.x;
    int w = tid >> 6, l = tid & 63, lg = l >> 4, lr = l & 15;
    int wq = w & 3, jh = w >> 2;

    char* Cl = (char*)&Clds[0];

#pragma unroll
    for (int p = 0; p < 8; ++p) {
        int gidx = p * 512 + tid;
        int row = gidx >> 6, sl = gidx & 63;
        const f32x4* src = reinterpret_cast<const f32x4*>(cbn + (jcol + row) * CBND + sl * 8);
        f32x4 v0 = src[0], v1 = src[1];
        bf16x8 bv;
#pragma unroll
        for (int e = 0; e < 4; ++e) { bv[e] = (__bf16)v0[e]; bv[e + 4] = (__bf16)v1[e]; }
        *reinterpret_cast<bf16x8*>(Cl + row * 1024 + ((sl ^ (row & 7)) << 4)) = bv;
    }
    __syncthreads();

    int r7 = lr & 7;
    for (int q = 0; q < 4; ++q) {
        int cb = ch * 4 + q;
        int crow = cb * 64 + wq * 16;
        f32x4 acc0 = ZERO4, acc1 = ZERO4;
        for (int k0 = 0; k0 < CBND; k0 += 32) {
            bf16x8 afrag = *reinterpret_cast<const bf16x8*>(WT + (crow + lr) * CBND + k0 + lg * 8);
            int slot = (k0 >> 3) + lg;
            int row0 = jh * 32 + lr;
            bf16x8 b0 = *reinterpret_cast<const bf16x8*>(Cl + row0 * 1024 + ((slot ^ r7) << 4));
            bf16x8 b1 = *reinterpret_cast<const bf16x8*>(Cl + (row0 + 16) * 1024 + ((slot ^ r7) << 4));
            acc0 = MFMA16(afrag, b0, acc0);
            acc1 = MFMA16(afrag, b1, acc1);
        }
#pragma unroll
        for (int f = 0; f < 2; ++f) {
            f32x4 af = f ? acc1 : acc0;
#pragma unroll
            for (int r = 0; r < 4; ++r) {
                int c = crow + lg * 4 + r;
                int j = jcol + jh * 32 + f * 16 + lr;
                float val = af[r] + bvec[c];
                g_blk[(((j >> 3) * 512 + c) << 3) + (j & 7)] = f2bf(val * dinv[j]);
            }
        }
    }
}

// ---------------- conv: partial sums P[jh] = sum_{j in half} adj_ij * g[:,j] ----------------
// Round-15/17 structure + GEN-input prefetch (r10's proven LOADG/GENP split):
// fJ/sj for supertile st+1 are register-loaded during st, so GEN's serial
// chain loses the ~200cyc L2 load latency. Values & order bit-identical
// (absmax 0.00390625). +8 VGPR (gJ/gS), safe under (1024,4)'s 128 cap.

#define LOADB(T, R) { \
    const char* p = gB + (long)(T) * 65536; \
    R##0 = *reinterpret_cast<const u32x4*>(p); \
    R##1 = *reinterpret_cast<const u32x4*>(p + 16384); \
    R##2 = *reinterpret_cast<const u32x4*>(p + 32768); \
    R##3 = *reinterpret_cast<const u32x4*>(p + 49152); \
}

#define LOADG(ST) { \
    int jg = jbase + (ST) * 64 + jq8 * 16; \
    gJ = *reinterpret_cast<const bf16x8*>(bbn_bf + (jg + lr) * BBND + lg * 8); \
    gS = *reinterpret_cast<const f32x4*>(s + jg + lg * 4); \
}

#define GENP(WB) { \
    f32x4 dot = MFMA16(gJ, fragI, ZERO4); \
    u32 p0 = cvtpk(adj_eval(dot[0], si + gS[0]), adj_eval(dot[1], si + gS[1])); \
    u32 p1 = cvtpk(adj_eval(dot[2], si + gS[2]), adj_eval(dot[3], si + gS[3])); \
    *reinterpret_cast<u32x2*>(Ab + (WB) * ABUFB + gw) = (u32x2){p0, p1}; \
}

#define CONVP(RB, R) { \
    const char* Ar = Ab + (RB) * ABUFB; \
    bf16x8 t0l = *reinterpret_cast<const bf16x8*>(Ar + a0); \
    bf16x8 t0h = *reinterpret_cast<const bf16x8*>(Ar + a0 + 4096); \
    c00 = MFMA32(t0l, __builtin_bit_cast(bf16x8, R##0), c00); \
    c10 = MFMA32(t0h, __builtin_bit_cast(bf16x8, R##0), c10); \
    bf16x8 t1l = *reinterpret_cast<const bf16x8*>(Ar + a1); \
    bf16x8 t1h = *reinterpret_cast<const bf16x8*>(Ar + a1 + 4096); \
    c00 = MFMA32(t1l, __builtin_bit_cast(bf16x8, R##1), c00); \
    c10 = MFMA32(t1h, __builtin_bit_cast(bf16x8, R##1), c10); \
    bf16x8 t2l = *reinterpret_cast<const bf16x8*>(Ar + a2); \
    bf16x8 t2h = *reinterpret_cast<const bf16x8*>(Ar + a2 + 4096); \
    c00 = MFMA32(t2l, __builtin_bit_cast(bf16x8, R##2), c00); \
    c10 = MFMA32(t2h, __builtin_bit_cast(bf16x8, R##2), c10); \
    bf16x8 t3l = *reinterpret_cast<const bf16x8*>(Ar + a3); \
    bf16x8 t3h = *reinterpret_cast<const bf16x8*>(Ar + a3 + 4096); \
    c00 = MFMA32(t3l, __builtin_bit_cast(bf16x8, R##3), c00); \
    c10 = MFMA32(t3h, __builtin_bit_cast(bf16x8, R##3), c10); \
}

#define EPI(ACC, IH) { \
    _Pragma("unroll") \
    for (int reg = 0; reg < 16; ++reg) { \
        int rowD = (reg & 3) + 8 * (reg >> 2) + 4 * lh; \
        Pq[(long)(ibase + (IH) * 32 + rowD) * CBND + w * 32 + l31] = ACC[reg]; \
    } \
}

__global__ __launch_bounds__(1024, 4) void k_conv(const u16* __restrict__ bbn_bf,
                                                  const float* __restrict__ s,
                                                  const u16* __restrict__ g_blk,
                                                  float* __restrict__ P) {
    __shared__ __align__(16) u16 Alds[2][64 * 64];   // 2 x 8KB supertiles

    int bx = blockIdx.x;
    int jq = bx & 1;                   // j-half; constant per XCD (stride-8 dispatch)
    int it = bx >> 1;                  // 0..127
    int ibase = it * 64;
    int jbase = jq * JQ;

    int tid = threadIdx.x;
    int w = tid >> 6, l = tid & 63;
    int lr = l & 15, lg = l >> 4, l31 = l & 31, lh = l >> 5;
    int iq = w & 3, jq8 = w >> 2;      // gen wave tile: 16i x 16j (4x4 waves)

    // gen hoists
    bf16x8 fragI = *reinterpret_cast<const bf16x8*>(bbn_bf + (ibase + iq * 16 + lr) * BBND + lg * 8);
    float si = s[ibase + iq * 16 + lr];

    char* Ab = (char*)&Alds[0][0];
    float* Pq = P + (long)jq * (NROWS * CBND);

    // B global base: octet (jbase/8 + T*8 + t*2 + lh), c = w*32 + l31
    const char* gB = (const char*)g_blk + (long)jbase * 1024 + lh * 8192
                   + (w * 32 + l31) * 16;

    // A-frag reads: rows l31 (i-lo) / l31+32 (i-hi, +4096B), k-step t slot = 2t+lh,
    // phys = slot ^ (row&7); (l31+32)&7 == l31&7 so i-hi shares the XOR.
    int r7 = l31 & 7;
    int abase = l31 * 128;
    int a0 = abase + (((0 + lh) ^ r7) << 4);
    int a1 = abase + (((2 + lh) ^ r7) << 4);
    int a2 = abase + (((4 + lh) ^ r7) << 4);
    int a3 = abase + (((6 + lh) ^ r7) << 4);

    // gen write: row = iq*16+lr, logical slot = jq8*2 + (lg>>1), byte +(lg&1)*8
    int grow = iq * 16 + lr;
    int gw = grow * 128 + (((jq8 * 2 + (lg >> 1)) ^ (grow & 7)) << 4) + (lg & 1) * 8;

    f32x16 c00 = ZERO16, c10 = ZERO16;

    u32x4 rA0, rA1, rA2, rA3;
    u32x4 rB0, rB1, rB2, rB3;
    bf16x8 gJ;
    f32x4 gS;

    // prologue: gen st0 into buf0 (inputs loaded then consumed), prefetch
    // gen inputs for st1, B(st0) into rA
    LOADG(0);
    GENP(0);
    LOADG(1);
    LOADB(0, rA);
    BAR;

    for (int st2 = 0; st2 < NR; st2 += 2) {
        // first half: gen st2+1 (prefetched inputs) into buf1, refill for st2+2
        LOADB(st2 + 1, rB);
        GENP(1);
        if (st2 + 2 < NR) LOADG(st2 + 2);
        CONVP(0, rA);
        BAR;
        // second half: gen st2+2 into buf0, refill for st2+3
        int tn = (st2 + 2 < NR) ? st2 + 2 : NR - 1;   // tail: redundant, never read
        LOADB(tn, rA);
        if (st2 + 2 < NR) {
            GENP(0);
            if (st2 + 3 < NR) LOADG(st2 + 3);
        }
        CONVP(1, rB);
        BAR;
    }

    EPI(c00, 0);
    EPI(c10, 1);
}

// ---------------- combine: out = sigmoid(dinv_i * (P0 + P1)) ----------------
__global__ __launch_bounds__(256) void k_comb(const float* __restrict__ dinv,
                                              const float* __restrict__ P,
                                              float* __restrict__ out) {
    int idx = blockIdx.x * 256 + threadIdx.x;   // f32x4 index; 1,048,576 total
    float di = dinv[idx >> 7];
    f32x4 a = *reinterpret_cast<const f32x4*>(P + (long)idx * 4);
    f32x4 b = *reinterpret_cast<const f32x4*>(P + (long)NROWS * CBND + (long)idx * 4);
    f32x4 v;
#pragma unroll
    for (int e = 0; e < 4; ++e) v[e] = sigmoidf_fast((a[e] + b[e]) * di);
    *reinterpret_cast<f32x4*>(out + (long)idx * 4) = v;
}

extern "C" void kernel_launch(void* const* d_in, const int* in_sizes, int n_in,
                              void* d_out, int out_size, void* d_ws, size_t ws_size,
                              hipStream_t stream) {
    const float* bbn = (const float*)d_in[0];   // [8192,32]
    const float* cbn = (const float*)d_in[1];   // [8192,512]
    const float* W   = (const float*)d_in[2];   // [512,512]
    const float* b   = (const float*)d_in[3];   // [512]
    float* out = (float*)d_out;                 // [8192,512] f32

    char* ws = (char*)d_ws;
    float* s      = (float*)ws;  ws += NROWS * 4;
    float* dinv   = (float*)ws;  ws += NROWS * 4;
    u16* bbn_bf   = (u16*)ws;    ws += NROWS * BBND * 2;
    u16* WT       = (u16*)ws;    ws += CBND * CBND * 2;
    u16* g_blk    = (u16*)ws;    ws += (size_t)CBND * NROWS * 2;
    float* P      = (float*)ws;  ws += (size_t)2 * NROWS * CBND * 4;   // 32MB partials

    k_prep_rows<<<NROWS / 256, 256, 0, stream>>>(bbn, s, bbn_bf);
    k_prep_wt<<<(CBND * CBND) / 256, 256, 0, stream>>>(W, WT);
    k_deg<<<NROWS / 16, 1024, 0, stream>>>(bbn_bf, s, dinv);
    k_fc<<<(NROWS / 64) * 2, 512, 0, stream>>>(cbn, WT, b, dinv, g_blk);
    k_conv<<<(NROWS / 64) * 2, 1024, 0, stream>>>(bbn_bf, s, g_blk, P);
    k_comb<<<(NROWS * CBND / 4) / 256, 256, 0, stream>>>(dinv, P, out);
}